// Round 3
// baseline (44395.889 us; speedup 1.0000x reference)
//
#include <hip/hip_runtime.h>
#include <math.h>

#define HF 32
#define WF 128
#define HW 4096
#define C_DIM 684
#define H_DIM 256
#define A_DIM 512
#define V_DIM 415
#define PADR 42
#define PADC 144
#define T_STEPS 64
#define NSEG 16
#define NBLK 256
#define NCTX2 86   // 86 blocks x 8 channels >= 684

// ---------------- workspace layout (float offsets) ----------------
constexpr int CT_OFF      = 0;                           // cnn_trans [hw][a]
constexpr int KM_OFF      = CT_OFF + HW * A_DIM;         // merged kernel [121][512]
constexpr int APAD_OFF    = KM_OFF + 121 * A_DIM;        // padded alpha_sum [42][144]
constexpr int MASK_OFF    = APAD_OFF + PADR * PADC;      // [4096]
constexpr int EXP_OFF     = MASK_OFF + HW;               // exp(energy) [4096]
constexpr int AVG_OFF     = EXP_OFF + HW;                // [684] pad 704
constexpr int H0_OFF      = AVG_OFF + 704;               // h0 [256]
constexpr int H1_OFF      = H0_OFF + 256;                // h1(t) [256]
constexpr int MSUM_OFF    = H1_OFF + 256;                // [1] pad 16
constexpr int WORDS_OFF   = MSUM_OFF + 16;               // 65 int slots, pad 80
constexpr int FLAGS_OFF   = WORDS_OFF + 80;              // 256 flags * 16 ints (1 line each)
constexpr int GENR_OFF    = FLAGS_OFF + 256 * 16;        // 8 gen replicas * 16 ints
constexpr int PSUM_OFF    = GENR_OFF + 8 * 16;           // [256] per-block exp sums
constexpr int PQ_OFF      = PSUM_OFF + 256;              // [16][512]
constexpr int PGHO_OFF    = PQ_OFF + NSEG * 512;         // [16][768]
constexpr int PGIO2_OFF   = PGHO_OFF + NSEG * 768;       // [86][768]
constexpr int PSC2_OFF    = PGIO2_OFF + NCTX2 * 768;     // [86][128]
constexpr int GI_OFF      = PSC2_OFF + NCTX2 * 128;      // [415][768]
constexpr int SE_OFF      = GI_OFF + V_DIM * 768;        // [415][128]
constexpr int WQT_OFF     = SE_OFF + V_DIM * 128;        // [256][512]
constexpr int WHHTOUT_OFF = WQT_OFF + 256 * 512;         // [256][768]
constexpr int WIHTOUT_OFF = WHHTOUT_OFF + 256 * 768;     // [684][768]
constexpr int WCT_OFF     = WIHTOUT_OFF + 684 * 768;     // [684][128]
constexpr int WST_OFF     = WCT_OFF + 684 * 128;         // [256][128]
constexpr int WVT_OFF     = WST_OFF + 256 * 128;         // [128][415]
constexpr int WS_END      = WVT_OFF + 128 * V_DIM;       // ~3.7M floats

__device__ __forceinline__ float sigmoidf_(float x) { return 1.f / (1.f + expf(-x)); }
__device__ __forceinline__ float ftanh(float x) {
  float e = __expf(2.f * x);
  return 1.f - 2.f / (e + 1.f);
}

// ---- contention-free grid barrier: per-block flag lines + replicated gen ----
__device__ __forceinline__ void gbar2(int* flags, int* genr, int ph) {
  __syncthreads();
  const int tid = threadIdx.x, bid = blockIdx.x;
  if (bid == 0) {
    if (tid >= 1 && tid < NBLK) {
      while (__hip_atomic_load(&flags[tid * 16], __ATOMIC_ACQUIRE, __HIP_MEMORY_SCOPE_AGENT) < ph)
        __builtin_amdgcn_s_sleep(1);
    }
    __syncthreads();
    if (tid < 8)
      __hip_atomic_store(&genr[tid * 16], ph, __ATOMIC_RELEASE, __HIP_MEMORY_SCOPE_AGENT);
  } else {
    if (tid == 0) {
      __hip_atomic_store(&flags[bid * 16], ph, __ATOMIC_RELEASE, __HIP_MEMORY_SCOPE_AGENT);
      while (__hip_atomic_load(&genr[(bid & 7) * 16], __ATOMIC_ACQUIRE, __HIP_MEMORY_SCOPE_AGENT) < ph)
        __builtin_amdgcn_s_sleep(2);
    }
    __syncthreads();
  }
}

// ---------------- precompute kernels ----------------

__global__ void k_init(const float* __restrict__ imask, float* ws) {
  __shared__ float red[4];
  int tid = threadIdx.x;
  float s = 0.f;
  for (int i = tid; i < HW; i += 256) {
    int h = i >> 7, w = i & 127;
    float m = imask[h * 16 * 2048 + w * 16];
    ws[MASK_OFF + i] = m;
    s += m;
  }
  for (int i = tid; i < PADR * PADC; i += 256) ws[APAD_OFF + i] = 0.f;
  int* flags = (int*)(ws + FLAGS_OFF);
  for (int i = tid; i < 256 * 16; i += 256) flags[i] = 0;
  int* genr = (int*)(ws + GENR_OFF);
  if (tid < 8 * 16) genr[tid] = 0;
  int* words = (int*)(ws + WORDS_OFF);
  if (tid < 65) words[tid] = (tid == 0) ? 1 : -1;
#pragma unroll
  for (int off = 32; off; off >>= 1) s += __shfl_xor(s, off, 64);
  if ((tid & 63) == 0) red[tid >> 6] = s;
  __syncthreads();
  if (tid == 0) ws[MSUM_OFF] = red[0] + red[1] + red[2] + red[3];
}

__global__ void k_avg(const float* __restrict__ cnn, float* ws) {
  __shared__ float red[4];
  int c = blockIdx.x, tid = threadIdx.x;
  const float* row = cnn + c * HW;
  float s = 0.f;
  for (int i = tid; i < HW; i += 256) s += ws[MASK_OFF + i] * row[i];
#pragma unroll
  for (int off = 32; off; off >>= 1) s += __shfl_xor(s, off, 64);
  if ((tid & 63) == 0) red[tid >> 6] = s;
  __syncthreads();
  if (tid == 0) ws[AVG_OFF + c] = (red[0] + red[1] + red[2] + red[3]) / ws[MSUM_OFF];
}

__global__ void k_h0(const float* __restrict__ W_init, const float* __restrict__ b_init, float* ws) {
  __shared__ float a_s[C_DIM];
  int tid = threadIdx.x;
  for (int i = tid; i < C_DIM; i += 256) a_s[i] = ws[AVG_OFF + i];
  __syncthreads();
  const float* wr = W_init + tid * C_DIM;
  float s = b_init[tid];
  for (int k = 0; k < C_DIM; k++) s += a_s[k] * wr[k];
  ws[H0_OFF + tid] = tanhf(s);
}

__global__ __launch_bounds__(512) void k_km(const float* __restrict__ convk,
                                            const float* __restrict__ Wcov, float* ws) {
  __shared__ float kt[256];
  int t = blockIdx.x, a = threadIdx.x;
  if (a < 256) kt[a] = convk[a * 121 + t];
  __syncthreads();
  const float* wr = Wcov + a * 256;
  float s = 0.f;
  for (int c = 0; c < 256; c++) s += kt[c] * wr[c];
  ws[KM_OFF + t * A_DIM + a] = s;
}

__global__ void k_ct(const float* __restrict__ cnn, const float* __restrict__ Wproj,
                     const float* __restrict__ bproj, float* ws) {
  __shared__ float As[8][128];
  __shared__ float Bs[8][64];
  int hw0 = blockIdx.x * 128;
  int a0 = blockIdx.y * 64;
  int tid = threadIdx.x;
  int tx = tid & 15, ty = tid >> 4;
  float acc[8][4];
#pragma unroll
  for (int i = 0; i < 8; i++)
#pragma unroll
    for (int j = 0; j < 4; j++) acc[i][j] = 0.f;

  for (int c0 = 0; c0 < C_DIM; c0 += 8) {
    {
      int kk = tid >> 5;
      int m4 = (tid & 31) * 4;
      int c = c0 + kk;
      float4 v = make_float4(0.f, 0.f, 0.f, 0.f);
      if (c < C_DIM) v = *(const float4*)(cnn + c * HW + hw0 + m4);
      *(float4*)&As[kk][m4] = v;
    }
    {
      int n = tid & 63;
      int kk0 = (tid >> 6) * 2;
      const float* wr = Wproj + (a0 + n) * C_DIM + c0;
      Bs[kk0][n]     = (c0 + kk0 < C_DIM) ? wr[kk0] : 0.f;
      Bs[kk0 + 1][n] = (c0 + kk0 + 1 < C_DIM) ? wr[kk0 + 1] : 0.f;
    }
    __syncthreads();
#pragma unroll
    for (int kk = 0; kk < 8; kk++) {
      float a8[8], b4[4];
#pragma unroll
      for (int i = 0; i < 8; i++) a8[i] = As[kk][ty * 8 + i];
#pragma unroll
      for (int j = 0; j < 4; j++) b4[j] = Bs[kk][tx * 4 + j];
#pragma unroll
      for (int i = 0; i < 8; i++)
#pragma unroll
        for (int j = 0; j < 4; j++) acc[i][j] += a8[i] * b4[j];
    }
    __syncthreads();
  }
#pragma unroll
  for (int i = 0; i < 8; i++) {
    int hw = hw0 + ty * 8 + i;
#pragma unroll
    for (int j = 0; j < 4; j++) {
      int a = a0 + tx * 4 + j;
      ws[CT_OFF + hw * A_DIM + a] = acc[i][j] + bproj[a];
    }
  }
}

__global__ void k_gi(const float* __restrict__ emb_table, const float* __restrict__ Wih_in,
                     const float* __restrict__ bih_in, float* ws) {
  __shared__ float e_s[256];
  int v = blockIdx.x, tid = threadIdx.x;
  e_s[tid] = emb_table[v * 256 + tid];
  __syncthreads();
#pragma unroll
  for (int r = 0; r < 3; r++) {
    int m = r * 256 + tid;
    const float* wr = Wih_in + m * 256;
    float s = bih_in[m];
    for (int k = 0; k < 256; k++) s += e_s[k] * wr[k];
    ws[GI_OFF + v * 768 + m] = s;
  }
}

__global__ void k_se(const float* __restrict__ emb_table, const float* __restrict__ We,
                     const float* __restrict__ be, float* ws) {
  __shared__ float e_s[256];
  int v = blockIdx.x, tid = threadIdx.x;  // 128 threads
  e_s[tid] = emb_table[v * 256 + tid];
  e_s[tid + 128] = emb_table[v * 256 + tid + 128];
  __syncthreads();
  const float* wr = We + tid * 256;
  float s = be[tid];
  for (int k = 0; k < 256; k++) s += e_s[k] * wr[k];
  ws[SE_OFF + v * 128 + tid] = s;
}

__global__ void k_tr(const float* __restrict__ in, float* __restrict__ out, int M, int Kd) {
  int total = M * Kd;
  for (int i = blockIdx.x * blockDim.x + threadIdx.x; i < total; i += gridDim.x * blockDim.x) {
    int m = i / Kd, k = i - m * Kd;
    out[k * M + m] = in[i];
  }
}

// step-0 bootstrap: h1(0) slice + q(0)/gho(0) partials, from h0 and word=1
__global__ __launch_bounds__(512) void k_pre0(const float* __restrict__ Whh_in,
                                              const float* __restrict__ bhh_in, float* ws) {
  __shared__ float sm_hh[256];
  __shared__ float sm_ghn[48];
  __shared__ float sm_h1s[16];
  const int bid = blockIdx.x, tid = threadIdx.x;
  const int j0 = bid * 16;
  if (tid < 256) sm_hh[tid] = ws[H0_OFF + tid];
  __syncthreads();
  {
    int r = tid >> 3, l = tid & 7;
    if (r < 48) {
      int gate = r >> 4, jj = r & 15;
      int mg = gate * 256 + j0 + jj;
      const float* wr = Whh_in + mg * 256 + l * 32;
      float s = 0.f;
#pragma unroll
      for (int k = 0; k < 32; k++) s += sm_hh[l * 32 + k] * wr[k];
#pragma unroll
      for (int off = 4; off; off >>= 1) s += __shfl_xor(s, off, 8);
      if (l == 0) sm_ghn[r] = s + bhh_in[mg];
    }
  }
  __syncthreads();
  if (tid < 16) {
    int j = j0 + tid;
    const float* gi = ws + GI_OFF + 1 * 768;  // word 1
    float r = sigmoidf_(gi[j] + sm_ghn[tid]);
    float z = sigmoidf_(gi[256 + j] + sm_ghn[16 + tid]);
    float n = tanhf(gi[512 + j] + r * sm_ghn[32 + tid]);
    float h1 = (1.f - z) * n + z * sm_hh[j];
    ws[H1_OFF + j] = h1;
    sm_h1s[tid] = h1;
  }
  __syncthreads();
  {
    float s = 0.f;
#pragma unroll
    for (int kk = 0; kk < 16; kk++) s += sm_h1s[kk] * ws[WQT_OFF + (j0 + kk) * 512 + tid];
    ws[PQ_OFF + bid * 512 + tid] = s;
  }
  for (int m = tid; m < 768; m += 512) {
    float s = 0.f;
#pragma unroll
    for (int kk = 0; kk < 16; kk++) s += sm_h1s[kk] * ws[WHHTOUT_OFF + (j0 + kk) * 768 + m];
    ws[PGHO_OFF + bid * 768 + m] = s;
  }
}

// ---------------- persistent all-steps kernel (3 barriers/step) ----------------

__global__ __launch_bounds__(512) void k_steps(
    const float* __restrict__ cnn, const float* __restrict__ Whh_in,
    const float* __restrict__ bq, const float* __restrict__ wa, const float* __restrict__ ba,
    const float* __restrict__ bih_out, const float* __restrict__ bhh_out,
    const float* __restrict__ bhh_in,
    const float* __restrict__ bs_, const float* __restrict__ bc_, const float* __restrict__ bv_,
    float* ws, float* __restrict__ out) {
  __shared__ float sm_gio[768], sm_gho[768];
  __shared__ float sm_h[256], sm_state[128];
  __shared__ float sm_patch[11][32];
  __shared__ float sm_red[8][16];
  __shared__ float sm_ctx[8];
  __shared__ float sm_ghn[48], sm_h1s[16];
  __shared__ float sm_val[512];
  __shared__ int sm_idx[512];
  __shared__ float sm_inv;
  __shared__ int sm_word;

  const int bid = blockIdx.x, tid = threadIdx.x;
  int* flags = (int*)(ws + FLAGS_OFF);
  int* genr  = (int*)(ws + GENR_OFF);
  int* words = (int*)(ws + WORDS_OFF);
  const int lane = tid & 63, wv = tid >> 6;
  int ph = 0;

#pragma unroll 1
  for (int t = 0; t < T_STEPS; t++) {
    // ---- P1: energy + exp (all 256 blocks, 16 hw each) ----
    {
      int h = bid >> 3, w0 = (bid & 7) * 16;
      int a = tid;
      float qa = bq[a];
#pragma unroll
      for (int s = 0; s < NSEG; s++) qa += ws[PQ_OFF + s * 512 + a];
      for (int i = tid; i < 11 * 26; i += 512) {
        int r = i / 26, c = i - r * 26;
        sm_patch[r][c] = ws[APAD_OFF + (h + r) * PADC + w0 + c];
      }
      __syncthreads();
      float acc[16];
#pragma unroll
      for (int i = 0; i < 16; i++) acc[i] = 0.f;
      const float* km = ws + KM_OFF;
      for (int dy = 0; dy < 11; dy++) {
        float row[26];
#pragma unroll
        for (int i = 0; i < 26; i++) row[i] = sm_patch[dy][i];
        float kv[11];
#pragma unroll
        for (int dx = 0; dx < 11; dx++) kv[dx] = km[(dy * 11 + dx) * A_DIM + a];
#pragma unroll
        for (int dx = 0; dx < 11; dx++)
#pragma unroll
          for (int wi = 0; wi < 16; wi++) acc[wi] += kv[dx] * row[wi + dx];
      }
      float waa = wa[a];
      int hw0 = h * WF + w0;
#pragma unroll
      for (int wi = 0; wi < 16; wi++) {
        float x = acc[wi] + qa + ws[CT_OFF + (hw0 + wi) * A_DIM + a];
        float p = ftanh(x) * waa;
#pragma unroll
        for (int off = 32; off; off >>= 1) p += __shfl_xor(p, off, 64);
        if (lane == 0) sm_red[wv][wi] = p;
      }
      __syncthreads();
      if (tid < 16) {
        float e = ba[0];
#pragma unroll
        for (int w2 = 0; w2 < 8; w2++) e += sm_red[w2][tid];
        int hw = hw0 + tid;
        float ev = (ws[MASK_OFF + hw] > 0.f) ? __expf(e) : 0.f;
        ws[EXP_OFF + hw] = ev;
        sm_val[tid] = ev;
      }
      __syncthreads();
      if (tid == 0) {
        float s = 0.f;
#pragma unroll
        for (int i = 0; i < 16; i++) s += sm_val[i];
        ws[PSUM_OFF + bid] = s;
      }
    }
    gbar2(flags, genr, ++ph);

    // ---- P2: ctx (86 blocks x 8ch) + gio/psc partials; apad update (86..93) ----
    if (bid < NCTX2 + 8) {
      // parallel softmax-sum reduce
      if (tid < 256) {
        float v = ws[PSUM_OFF + tid];
#pragma unroll
        for (int off = 32; off; off >>= 1) v += __shfl_xor(v, off, 64);
        if ((tid & 63) == 0) sm_red[0][tid >> 6] = v;
      }
      __syncthreads();
      if (tid == 0)
        sm_inv = 1.f / (sm_red[0][0] + sm_red[0][1] + sm_red[0][2] + sm_red[0][3]);
      __syncthreads();
      float inv = sm_inv;
      if (bid < NCTX2) {
        float al[8];
#pragma unroll
        for (int j = 0; j < 8; j++) al[j] = ws[EXP_OFF + j * 512 + tid] * inv;
        int c0 = bid * 8;
#pragma unroll
        for (int cc = 0; cc < 8; cc++) {
          int c = c0 + cc;
          float p = 0.f;
          if (c < C_DIM) {
            const float* row = cnn + c * HW;
#pragma unroll
            for (int j = 0; j < 8; j++) p += al[j] * row[j * 512 + tid];
          }
#pragma unroll
          for (int off = 32; off; off >>= 1) p += __shfl_xor(p, off, 64);
          if (lane == 0) sm_red[wv][cc] = p;
        }
        __syncthreads();
        if (tid < 8) {
          float cv = 0.f;
#pragma unroll
          for (int w2 = 0; w2 < 8; w2++) cv += sm_red[w2][tid];
          sm_ctx[tid] = cv;
        }
        __syncthreads();
        for (int m = tid; m < 768; m += 512) {
          float s = 0.f;
#pragma unroll
          for (int cc = 0; cc < 8; cc++) {
            int c = c0 + cc;
            int cw = (c < C_DIM) ? c : (C_DIM - 1);
            s += sm_ctx[cc] * ws[WIHTOUT_OFF + cw * 768 + m];
          }
          ws[PGIO2_OFF + bid * 768 + m] = s;
        }
        if (tid < 128) {
          float s = 0.f;
#pragma unroll
          for (int cc = 0; cc < 8; cc++) {
            int c = c0 + cc;
            int cw = (c < C_DIM) ? c : (C_DIM - 1);
            s += sm_ctx[cc] * ws[WCT_OFF + cw * 128 + tid];
          }
          ws[PSC2_OFF + bid * 128 + tid] = s;
        }
      } else {
        int idx = (bid - NCTX2) * 512 + tid;
        int hh = idx >> 7, ww = idx & 127;
        ws[APAD_OFF + (hh + 5) * PADC + ww + 5] += ws[EXP_OFF + idx] * inv;
      }
    }
    gbar2(flags, genr, ++ph);

    // ---- P3 (blocks 0..16): reduce -> h; blk16 state/prob/argmax/word;
    //      blks 0..15: gh_in slice, poll word, h1/q/gho for t+1 ----
    if (bid <= NSEG) {
      for (int m = tid; m < 768; m += 512) {
        float g1 = bih_out[m];
        for (int s = 0; s < NCTX2; s++) g1 += ws[PGIO2_OFF + s * 768 + m];
        float g2 = bhh_out[m];
#pragma unroll
        for (int s = 0; s < NSEG; s++) g2 += ws[PGHO_OFF + s * 768 + m];
        sm_gio[m] = g1;
        sm_gho[m] = g2;
      }
      __syncthreads();
      if (tid < 256) {
        float h1v = ws[H1_OFF + tid];
        float r = sigmoidf_(sm_gio[tid] + sm_gho[tid]);
        float z = sigmoidf_(sm_gio[256 + tid] + sm_gho[256 + tid]);
        float n = tanhf(sm_gio[512 + tid] + r * sm_gho[512 + tid]);
        sm_h[tid] = (1.f - z) * n + z * h1v;
      }
      __syncthreads();
      if (bid == NSEG) {
        int word = words[t];  // written >=1 barrier ago (or k_init)
        if (tid < 128) {
          float s = bs_[tid] + bc_[tid] + ws[SE_OFF + word * 128 + tid];
          for (int sg = 0; sg < NCTX2; sg++) s += ws[PSC2_OFF + sg * 128 + tid];
          for (int k = 0; k < 256; k++) s += sm_h[k] * ws[WST_OFF + k * 128 + tid];
          sm_state[tid] = s;
        }
        __syncthreads();
        float best = -3.4e38f;
        int bi2 = 0;
        if (tid < V_DIM) {
          float p = bv_[tid];
          for (int k = 0; k < 128; k++) p += sm_state[k] * ws[WVT_OFF + k * V_DIM + tid];
          out[t * V_DIM + tid] = p;
          best = p;
          bi2 = tid;
        }
        sm_val[tid] = best;
        sm_idx[tid] = bi2;
        __syncthreads();
        for (int mstep = 256; mstep >= 1; mstep >>= 1) {
          if (tid < mstep) {
            float ov = sm_val[tid + mstep];
            int oi = sm_idx[tid + mstep];
            if (ov > sm_val[tid] || (ov == sm_val[tid] && oi < sm_idx[tid])) {
              sm_val[tid] = ov;
              sm_idx[tid] = oi;
            }
          }
          __syncthreads();
        }
        if (tid == 0)
          __hip_atomic_store(&words[t + 1], sm_idx[0], __ATOMIC_RELEASE, __HIP_MEMORY_SCOPE_AGENT);
      } else {
        // blocks 0..15: Whh_in slice from h(t)
        const int j0 = bid * 16;
        {
          int r = tid >> 3, l = tid & 7;
          if (r < 48) {
            int gate = r >> 4, jj = r & 15;
            int mg = gate * 256 + j0 + jj;
            const float* wr = Whh_in + mg * 256 + l * 32;
            float s = 0.f;
#pragma unroll
            for (int k = 0; k < 32; k++) s += sm_h[l * 32 + k] * wr[k];
#pragma unroll
            for (int off = 4; off; off >>= 1) s += __shfl_xor(s, off, 8);
            if (l == 0) sm_ghn[r] = s + bhh_in[mg];
          }
        }
        if (tid == 0) {
          int w;
          while ((w = __hip_atomic_load(&words[t + 1], __ATOMIC_ACQUIRE, __HIP_MEMORY_SCOPE_AGENT)) < 0)
            __builtin_amdgcn_s_sleep(1);
          sm_word = w;
        }
        __syncthreads();
        int wnew = sm_word;
        if (tid < 16) {
          int j = j0 + tid;
          const float* gi = ws + GI_OFF + wnew * 768;
          float r = sigmoidf_(gi[j] + sm_ghn[tid]);
          float z = sigmoidf_(gi[256 + j] + sm_ghn[16 + tid]);
          float n = tanhf(gi[512 + j] + r * sm_ghn[32 + tid]);
          float h1 = (1.f - z) * n + z * sm_h[j];
          ws[H1_OFF + j] = h1;
          sm_h1s[tid] = h1;
        }
        __syncthreads();
        {
          float s = 0.f;
#pragma unroll
          for (int kk = 0; kk < 16; kk++) s += sm_h1s[kk] * ws[WQT_OFF + (j0 + kk) * 512 + tid];
          ws[PQ_OFF + bid * 512 + tid] = s;
        }
        for (int m = tid; m < 768; m += 512) {
          float s = 0.f;
#pragma unroll
          for (int kk = 0; kk < 16; kk++) s += sm_h1s[kk] * ws[WHHTOUT_OFF + (j0 + kk) * 768 + m];
          ws[PGHO_OFF + bid * 768 + m] = s;
        }
      }
    }
    gbar2(flags, genr, ++ph);
  }
}

// ---------------- host ----------------

extern "C" void kernel_launch(void* const* d_in, const int* in_sizes, int n_in,
                              void* d_out, int out_size, void* d_ws, size_t ws_size,
                              hipStream_t stream) {
  (void)in_sizes; (void)n_in; (void)out_size; (void)ws_size;
  const float* cnn      = (const float*)d_in[0];
  const float* imask    = (const float*)d_in[1];
  const float* emb_tab  = (const float*)d_in[2];
  const float* W_init   = (const float*)d_in[3];
  const float* b_init   = (const float*)d_in[4];
  const float* Wih_in   = (const float*)d_in[5];
  const float* Whh_in   = (const float*)d_in[6];
  const float* bih_in   = (const float*)d_in[7];
  const float* bhh_in   = (const float*)d_in[8];
  const float* Wih_out  = (const float*)d_in[9];
  const float* Whh_out  = (const float*)d_in[10];
  const float* bih_out  = (const float*)d_in[11];
  const float* bhh_out  = (const float*)d_in[12];
  const float* Wq       = (const float*)d_in[13];
  const float* bq       = (const float*)d_in[14];
  const float* Wproj    = (const float*)d_in[15];
  const float* bproj    = (const float*)d_in[16];
  const float* convk    = (const float*)d_in[17];
  const float* Wcov     = (const float*)d_in[18];
  const float* wa       = (const float*)d_in[19];
  const float* ba       = (const float*)d_in[20];
  const float* Ws_      = (const float*)d_in[21];
  const float* bs_      = (const float*)d_in[22];
  const float* We_      = (const float*)d_in[23];
  const float* be_      = (const float*)d_in[24];
  const float* Wc_      = (const float*)d_in[25];
  const float* bc_      = (const float*)d_in[26];
  const float* Wv_      = (const float*)d_in[27];
  const float* bv_      = (const float*)d_in[28];
  float* ws  = (float*)d_ws;
  float* out = (float*)d_out;

  // one-time precompute
  k_init<<<1, 256, 0, stream>>>(imask, ws);
  k_avg<<<C_DIM, 256, 0, stream>>>(cnn, ws);
  k_h0<<<1, 256, 0, stream>>>(W_init, b_init, ws);
  k_km<<<121, 512, 0, stream>>>(convk, Wcov, ws);
  k_ct<<<dim3(HW / 128, A_DIM / 64), 256, 0, stream>>>(cnn, Wproj, bproj, ws);
  k_gi<<<V_DIM, 256, 0, stream>>>(emb_tab, Wih_in, bih_in, ws);
  k_se<<<V_DIM, 128, 0, stream>>>(emb_tab, We_, be_, ws);
  k_tr<<<512, 256, 0, stream>>>(Wq, ws + WQT_OFF, 512, 256);
  k_tr<<<512, 256, 0, stream>>>(Whh_out, ws + WHHTOUT_OFF, 768, 256);
  k_tr<<<512, 256, 0, stream>>>(Wih_out, ws + WIHTOUT_OFF, 768, 684);
  k_tr<<<512, 256, 0, stream>>>(Wc_, ws + WCT_OFF, 128, 684);
  k_tr<<<512, 256, 0, stream>>>(Ws_, ws + WST_OFF, 128, 256);
  k_tr<<<512, 256, 0, stream>>>(Wv_, ws + WVT_OFF, 415, 128);
  k_pre0<<<NSEG, 512, 0, stream>>>(Whh_in, bhh_in, ws);

  // all 64 steps in one persistent kernel
  k_steps<<<NBLK, 512, 0, stream>>>(cnn, Whh_in, bq, wa, ba, bih_out, bhh_out, bhh_in,
                                    bs_, bc_, bv_, ws, out);
}

// Round 4
// 13785.982 us; speedup vs baseline: 3.2204x; 3.2204x over previous
//
#include <hip/hip_runtime.h>
#include <math.h>

#define HF 32
#define WF 128
#define HW 4096
#define C_DIM 684
#define H_DIM 256
#define A_DIM 512
#define V_DIM 415
#define PADR 42
#define PADC 144
#define T_STEPS 64
#define NSEG 16
#define NBLK 256
#define NCTX2 86   // 86 blocks x 8 channels >= 684
#define NP2 (NCTX2 + 8)   // P2 participants: 86 ctx + 8 apad = 94

// ---------------- workspace layout (float offsets) ----------------
constexpr int CT_OFF      = 0;                           // cnn_trans [hw][a]
constexpr int KM_OFF      = CT_OFF + HW * A_DIM;         // merged kernel [121][512]
constexpr int APAD_OFF    = KM_OFF + 121 * A_DIM;        // padded alpha_sum [42][144]
constexpr int MASK_OFF    = APAD_OFF + PADR * PADC;      // [4096]
constexpr int EXP_OFF     = MASK_OFF + HW;               // exp(energy) [4096]
constexpr int AVG_OFF     = EXP_OFF + HW;                // [684] pad 704
constexpr int H0_OFF      = AVG_OFF + 704;               // h0 [256]
constexpr int H1_OFF      = H0_OFF + 256;                // h1(t) [256]
constexpr int MSUM_OFF    = H1_OFF + 256;                // [1] pad 16
constexpr int WORDS_OFF   = MSUM_OFF + 16;               // 65 int slots, pad 80
constexpr int FLAGS_OFF   = WORDS_OFF + 80;              // 256 flags * 16 ints (1 line each)
constexpr int GENR_OFF    = FLAGS_OFF + 256 * 16;        // 8 gen replicas * 16 ints
constexpr int PSUM_OFF    = GENR_OFF + 8 * 16;           // [256] per-block exp sums
constexpr int PQ_OFF      = PSUM_OFF + 256;              // [16][512]
constexpr int PGHO_OFF    = PQ_OFF + NSEG * 512;         // [16][768]
constexpr int PGIO2_OFF   = PGHO_OFF + NSEG * 768;       // [86][768]
constexpr int PSC2_OFF    = PGIO2_OFF + NCTX2 * 768;     // [86][128]
constexpr int GI_OFF      = PSC2_OFF + NCTX2 * 128;      // [415][768]
constexpr int SE_OFF      = GI_OFF + V_DIM * 768;        // [415][128]
constexpr int WQT_OFF     = SE_OFF + V_DIM * 128;        // [256][512]
constexpr int WHHTOUT_OFF = WQT_OFF + 256 * 512;         // [256][768]
constexpr int WIHTOUT_OFF = WHHTOUT_OFF + 256 * 768;     // [684][768]
constexpr int WCT_OFF     = WIHTOUT_OFF + 684 * 768;     // [684][128]
constexpr int WST_OFF     = WCT_OFF + 684 * 128;         // [256][128]
constexpr int WVT_OFF     = WST_OFF + 256 * 128;         // [128][415]
constexpr int WS_END      = WVT_OFF + 128 * V_DIM;       // ~3.7M floats

__device__ __forceinline__ float sigmoidf_(float x) { return 1.f / (1.f + expf(-x)); }
__device__ __forceinline__ float ftanh(float x) {
  float e = __expf(2.f * x);
  return 1.f - 2.f / (e + 1.f);
}

// ---- backoff sleep: ~100ns -> ~0.4us -> ~1.7us cap ----
__device__ __forceinline__ void bk_sleep(int it) {
  if (it < 2) __builtin_amdgcn_s_sleep(2);
  else if (it < 6) __builtin_amdgcn_s_sleep(16);
  else __builtin_amdgcn_s_sleep(64);
}

// relaxed-poll until *p >= ph, then one acquire load (round-2-proven visibility)
__device__ __forceinline__ void poll_ge(int* p, int ph) {
  int it = 0;
  while (__hip_atomic_load(p, __ATOMIC_RELAXED, __HIP_MEMORY_SCOPE_AGENT) < ph) {
    bk_sleep(it); ++it;
  }
  (void)__hip_atomic_load(p, __ATOMIC_ACQUIRE, __HIP_MEMORY_SCOPE_AGENT);
}

// block 0 only: wait for producers 1..nprod-1, then publish gen=ph (8 replicas)
__device__ __forceinline__ void collect_publish(int* flags, int* genr, int nprod, int ph) {
  __syncthreads();
  const int tid = threadIdx.x;
  if (tid >= 1 && tid < nprod) poll_ge(&flags[tid * 16], ph);
  __syncthreads();
  if (tid < 8)
    __hip_atomic_store(&genr[tid * 16], ph, __ATOMIC_RELEASE, __HIP_MEMORY_SCOPE_AGENT);
}

// producer arrival: own cache line, release store, no RMW, no wait
__device__ __forceinline__ void bar_arrive(int* flags, int ph) {
  __syncthreads();  // all block threads' writes issued+drained before flag release
  if (threadIdx.x == 0)
    __hip_atomic_store(&flags[blockIdx.x * 16], ph, __ATOMIC_RELEASE, __HIP_MEMORY_SCOPE_AGENT);
}

// consumer wait on replicated gen line
__device__ __forceinline__ void bar_waitgen(int* genr, int ph) {
  if (threadIdx.x == 0) poll_ge(&genr[(blockIdx.x & 7) * 16], ph);
  __syncthreads();
}

// ---------------- precompute kernels ----------------

__global__ void k_init(const float* __restrict__ imask, float* ws) {
  __shared__ float red[4];
  int tid = threadIdx.x;
  float s = 0.f;
  for (int i = tid; i < HW; i += 256) {
    int h = i >> 7, w = i & 127;
    float m = imask[h * 16 * 2048 + w * 16];
    ws[MASK_OFF + i] = m;
    s += m;
  }
  for (int i = tid; i < PADR * PADC; i += 256) ws[APAD_OFF + i] = 0.f;
  int* flags = (int*)(ws + FLAGS_OFF);
  for (int i = tid; i < 256 * 16; i += 256) flags[i] = 0;
  int* genr = (int*)(ws + GENR_OFF);
  if (tid < 8 * 16) genr[tid] = 0;
  int* words = (int*)(ws + WORDS_OFF);
  if (tid < 65) words[tid] = (tid == 0) ? 1 : -1;
#pragma unroll
  for (int off = 32; off; off >>= 1) s += __shfl_xor(s, off, 64);
  if ((tid & 63) == 0) red[tid >> 6] = s;
  __syncthreads();
  if (tid == 0) ws[MSUM_OFF] = red[0] + red[1] + red[2] + red[3];
}

__global__ void k_avg(const float* __restrict__ cnn, float* ws) {
  __shared__ float red[4];
  int c = blockIdx.x, tid = threadIdx.x;
  const float* row = cnn + c * HW;
  float s = 0.f;
  for (int i = tid; i < HW; i += 256) s += ws[MASK_OFF + i] * row[i];
#pragma unroll
  for (int off = 32; off; off >>= 1) s += __shfl_xor(s, off, 64);
  if ((tid & 63) == 0) red[tid >> 6] = s;
  __syncthreads();
  if (tid == 0) ws[AVG_OFF + c] = (red[0] + red[1] + red[2] + red[3]) / ws[MSUM_OFF];
}

__global__ void k_h0(const float* __restrict__ W_init, const float* __restrict__ b_init, float* ws) {
  __shared__ float a_s[C_DIM];
  int tid = threadIdx.x;
  for (int i = tid; i < C_DIM; i += 256) a_s[i] = ws[AVG_OFF + i];
  __syncthreads();
  const float* wr = W_init + tid * C_DIM;
  float s = b_init[tid];
  for (int k = 0; k < C_DIM; k++) s += a_s[k] * wr[k];
  ws[H0_OFF + tid] = tanhf(s);
}

__global__ __launch_bounds__(512) void k_km(const float* __restrict__ convk,
                                            const float* __restrict__ Wcov, float* ws) {
  __shared__ float kt[256];
  int t = blockIdx.x, a = threadIdx.x;
  if (a < 256) kt[a] = convk[a * 121 + t];
  __syncthreads();
  const float* wr = Wcov + a * 256;
  float s = 0.f;
  for (int c = 0; c < 256; c++) s += kt[c] * wr[c];
  ws[KM_OFF + t * A_DIM + a] = s;
}

__global__ void k_ct(const float* __restrict__ cnn, const float* __restrict__ Wproj,
                     const float* __restrict__ bproj, float* ws) {
  __shared__ float As[8][128];
  __shared__ float Bs[8][64];
  int hw0 = blockIdx.x * 128;
  int a0 = blockIdx.y * 64;
  int tid = threadIdx.x;
  int tx = tid & 15, ty = tid >> 4;
  float acc[8][4];
#pragma unroll
  for (int i = 0; i < 8; i++)
#pragma unroll
    for (int j = 0; j < 4; j++) acc[i][j] = 0.f;

  for (int c0 = 0; c0 < C_DIM; c0 += 8) {
    {
      int kk = tid >> 5;
      int m4 = (tid & 31) * 4;
      int c = c0 + kk;
      float4 v = make_float4(0.f, 0.f, 0.f, 0.f);
      if (c < C_DIM) v = *(const float4*)(cnn + c * HW + hw0 + m4);
      *(float4*)&As[kk][m4] = v;
    }
    {
      int n = tid & 63;
      int kk0 = (tid >> 6) * 2;
      const float* wr = Wproj + (a0 + n) * C_DIM + c0;
      Bs[kk0][n]     = (c0 + kk0 < C_DIM) ? wr[kk0] : 0.f;
      Bs[kk0 + 1][n] = (c0 + kk0 + 1 < C_DIM) ? wr[kk0 + 1] : 0.f;
    }
    __syncthreads();
#pragma unroll
    for (int kk = 0; kk < 8; kk++) {
      float a8[8], b4[4];
#pragma unroll
      for (int i = 0; i < 8; i++) a8[i] = As[kk][ty * 8 + i];
#pragma unroll
      for (int j = 0; j < 4; j++) b4[j] = Bs[kk][tx * 4 + j];
#pragma unroll
      for (int i = 0; i < 8; i++)
#pragma unroll
        for (int j = 0; j < 4; j++) acc[i][j] += a8[i] * b4[j];
    }
    __syncthreads();
  }
#pragma unroll
  for (int i = 0; i < 8; i++) {
    int hw = hw0 + ty * 8 + i;
#pragma unroll
    for (int j = 0; j < 4; j++) {
      int a = a0 + tx * 4 + j;
      ws[CT_OFF + hw * A_DIM + a] = acc[i][j] + bproj[a];
    }
  }
}

__global__ void k_gi(const float* __restrict__ emb_table, const float* __restrict__ Wih_in,
                     const float* __restrict__ bih_in, float* ws) {
  __shared__ float e_s[256];
  int v = blockIdx.x, tid = threadIdx.x;
  e_s[tid] = emb_table[v * 256 + tid];
  __syncthreads();
#pragma unroll
  for (int r = 0; r < 3; r++) {
    int m = r * 256 + tid;
    const float* wr = Wih_in + m * 256;
    float s = bih_in[m];
    for (int k = 0; k < 256; k++) s += e_s[k] * wr[k];
    ws[GI_OFF + v * 768 + m] = s;
  }
}

__global__ void k_se(const float* __restrict__ emb_table, const float* __restrict__ We,
                     const float* __restrict__ be, float* ws) {
  __shared__ float e_s[256];
  int v = blockIdx.x, tid = threadIdx.x;  // 128 threads
  e_s[tid] = emb_table[v * 256 + tid];
  e_s[tid + 128] = emb_table[v * 256 + tid + 128];
  __syncthreads();
  const float* wr = We + tid * 256;
  float s = be[tid];
  for (int k = 0; k < 256; k++) s += e_s[k] * wr[k];
  ws[SE_OFF + v * 128 + tid] = s;
}

__global__ void k_tr(const float* __restrict__ in, float* __restrict__ out, int M, int Kd) {
  int total = M * Kd;
  for (int i = blockIdx.x * blockDim.x + threadIdx.x; i < total; i += gridDim.x * blockDim.x) {
    int m = i / Kd, k = i - m * Kd;
    out[k * M + m] = in[i];
  }
}

// step-0 bootstrap: h1(0) slice + q(0)/gho(0) partials, from h0 and word=1
__global__ __launch_bounds__(512) void k_pre0(const float* __restrict__ Whh_in,
                                              const float* __restrict__ bhh_in, float* ws) {
  __shared__ float sm_hh[256];
  __shared__ float sm_ghn[48];
  __shared__ float sm_h1s[16];
  const int bid = blockIdx.x, tid = threadIdx.x;
  const int j0 = bid * 16;
  if (tid < 256) sm_hh[tid] = ws[H0_OFF + tid];
  __syncthreads();
  {
    int r = tid >> 3, l = tid & 7;
    if (r < 48) {
      int gate = r >> 4, jj = r & 15;
      int mg = gate * 256 + j0 + jj;
      const float* wr = Whh_in + mg * 256 + l * 32;
      float s = 0.f;
#pragma unroll
      for (int k = 0; k < 32; k++) s += sm_hh[l * 32 + k] * wr[k];
#pragma unroll
      for (int off = 4; off; off >>= 1) s += __shfl_xor(s, off, 8);
      if (l == 0) sm_ghn[r] = s + bhh_in[mg];
    }
  }
  __syncthreads();
  if (tid < 16) {
    int j = j0 + tid;
    const float* gi = ws + GI_OFF + 1 * 768;  // word 1
    float r = sigmoidf_(gi[j] + sm_ghn[tid]);
    float z = sigmoidf_(gi[256 + j] + sm_ghn[16 + tid]);
    float n = tanhf(gi[512 + j] + r * sm_ghn[32 + tid]);
    float h1 = (1.f - z) * n + z * sm_hh[j];
    ws[H1_OFF + j] = h1;
    sm_h1s[tid] = h1;
  }
  __syncthreads();
  {
    float s = 0.f;
#pragma unroll
    for (int kk = 0; kk < 16; kk++) s += sm_h1s[kk] * ws[WQT_OFF + (j0 + kk) * 512 + tid];
    ws[PQ_OFF + bid * 512 + tid] = s;
  }
  for (int m = tid; m < 768; m += 512) {
    float s = 0.f;
#pragma unroll
    for (int kk = 0; kk < 16; kk++) s += sm_h1s[kk] * ws[WHHTOUT_OFF + (j0 + kk) * 768 + m];
    ws[PGHO_OFF + bid * 768 + m] = s;
  }
}

// ---------------- persistent all-steps kernel (3 asymmetric barriers/step) ----------------
// bar1: 256 arrive, 94 wait.  bar2: 94 arrive, 17 wait.  bar3: 17 arrive, 256 wait.

__global__ __launch_bounds__(512) void k_steps(
    const float* __restrict__ cnn, const float* __restrict__ Whh_in,
    const float* __restrict__ bq, const float* __restrict__ wa, const float* __restrict__ ba,
    const float* __restrict__ bih_out, const float* __restrict__ bhh_out,
    const float* __restrict__ bhh_in,
    const float* __restrict__ bs_, const float* __restrict__ bc_, const float* __restrict__ bv_,
    float* ws, float* __restrict__ out) {
  __shared__ float sm_gio[768], sm_gho[768];
  __shared__ float sm_h[256], sm_state[128];
  __shared__ float sm_patch[11][32];
  __shared__ float sm_red[8][16];
  __shared__ float sm_ctx[8];
  __shared__ float sm_ghn[48], sm_h1s[16];
  __shared__ float sm_val[512];
  __shared__ int sm_idx[512];
  __shared__ float sm_inv;
  __shared__ int sm_word;

  const int bid = blockIdx.x, tid = threadIdx.x;
  int* flags = (int*)(ws + FLAGS_OFF);
  int* genr  = (int*)(ws + GENR_OFF);
  int* words = (int*)(ws + WORDS_OFF);
  const int lane = tid & 63, wv = tid >> 6;

#pragma unroll 1
  for (int t = 0; t < T_STEPS; t++) {
    const int ph1 = 3 * t + 1, ph2 = 3 * t + 2, ph3 = 3 * t + 3;

    // ---- P1: energy + exp (all 256 blocks, 16 hw each) ----
    {
      int h = bid >> 3, w0 = (bid & 7) * 16;
      int a = tid;
      float qa = bq[a];
#pragma unroll
      for (int s = 0; s < NSEG; s++) qa += ws[PQ_OFF + s * 512 + a];
      for (int i = tid; i < 11 * 26; i += 512) {
        int r = i / 26, c = i - r * 26;
        sm_patch[r][c] = ws[APAD_OFF + (h + r) * PADC + w0 + c];
      }
      __syncthreads();
      float acc[16];
#pragma unroll
      for (int i = 0; i < 16; i++) acc[i] = 0.f;
      const float* km = ws + KM_OFF;
      for (int dy = 0; dy < 11; dy++) {
        float row[26];
#pragma unroll
        for (int i = 0; i < 26; i++) row[i] = sm_patch[dy][i];
        float kv[11];
#pragma unroll
        for (int dx = 0; dx < 11; dx++) kv[dx] = km[(dy * 11 + dx) * A_DIM + a];
#pragma unroll
        for (int dx = 0; dx < 11; dx++)
#pragma unroll
          for (int wi = 0; wi < 16; wi++) acc[wi] += kv[dx] * row[wi + dx];
      }
      float waa = wa[a];
      int hw0 = h * WF + w0;
#pragma unroll
      for (int wi = 0; wi < 16; wi++) {
        float x = acc[wi] + qa + ws[CT_OFF + (hw0 + wi) * A_DIM + a];
        float p = ftanh(x) * waa;
#pragma unroll
        for (int off = 32; off; off >>= 1) p += __shfl_xor(p, off, 64);
        if (lane == 0) sm_red[wv][wi] = p;
      }
      __syncthreads();
      if (tid < 16) {
        float e = ba[0];
#pragma unroll
        for (int w2 = 0; w2 < 8; w2++) e += sm_red[w2][tid];
        int hw = hw0 + tid;
        float ev = (ws[MASK_OFF + hw] > 0.f) ? __expf(e) : 0.f;
        ws[EXP_OFF + hw] = ev;
        sm_val[tid] = ev;
      }
      __syncthreads();
      if (tid == 0) {
        float s = 0.f;
#pragma unroll
        for (int i = 0; i < 16; i++) s += sm_val[i];
        ws[PSUM_OFF + bid] = s;
      }
    }
    // bar1: all 256 arrive; P2 participants (0..93) wait
    if (bid == 0) {
      collect_publish(flags, genr, NBLK, ph1);
    } else {
      bar_arrive(flags, ph1);
      if (bid < NP2) bar_waitgen(genr, ph1);
    }

    // ---- P2: ctx (86 blocks x 8ch) + gio/psc partials; apad update (86..93) ----
    if (bid < NP2) {
      if (tid < 256) {
        float v = ws[PSUM_OFF + tid];
#pragma unroll
        for (int off = 32; off; off >>= 1) v += __shfl_xor(v, off, 64);
        if ((tid & 63) == 0) sm_red[0][tid >> 6] = v;
      }
      __syncthreads();
      if (tid == 0)
        sm_inv = 1.f / (sm_red[0][0] + sm_red[0][1] + sm_red[0][2] + sm_red[0][3]);
      __syncthreads();
      float inv = sm_inv;
      if (bid < NCTX2) {
        float al[8];
#pragma unroll
        for (int j = 0; j < 8; j++) al[j] = ws[EXP_OFF + j * 512 + tid] * inv;
        int c0 = bid * 8;
#pragma unroll
        for (int cc = 0; cc < 8; cc++) {
          int c = c0 + cc;
          float p = 0.f;
          if (c < C_DIM) {
            const float* row = cnn + c * HW;
#pragma unroll
            for (int j = 0; j < 8; j++) p += al[j] * row[j * 512 + tid];
          }
#pragma unroll
          for (int off = 32; off; off >>= 1) p += __shfl_xor(p, off, 64);
          if (lane == 0) sm_red[wv][cc] = p;
        }
        __syncthreads();
        if (tid < 8) {
          float cv = 0.f;
#pragma unroll
          for (int w2 = 0; w2 < 8; w2++) cv += sm_red[w2][tid];
          sm_ctx[tid] = cv;
        }
        __syncthreads();
        for (int m = tid; m < 768; m += 512) {
          float s = 0.f;
#pragma unroll
          for (int cc = 0; cc < 8; cc++) {
            int c = c0 + cc;
            int cw = (c < C_DIM) ? c : (C_DIM - 1);
            s += sm_ctx[cc] * ws[WIHTOUT_OFF + cw * 768 + m];
          }
          ws[PGIO2_OFF + bid * 768 + m] = s;
        }
        if (tid < 128) {
          float s = 0.f;
#pragma unroll
          for (int cc = 0; cc < 8; cc++) {
            int c = c0 + cc;
            int cw = (c < C_DIM) ? c : (C_DIM - 1);
            s += sm_ctx[cc] * ws[WCT_OFF + cw * 128 + tid];
          }
          ws[PSC2_OFF + bid * 128 + tid] = s;
        }
      } else {
        int idx = (bid - NCTX2) * 512 + tid;
        int hh = idx >> 7, ww = idx & 127;
        ws[APAD_OFF + (hh + 5) * PADC + ww + 5] += ws[EXP_OFF + idx] * inv;
      }
      // bar2: 94 arrive; P3 participants (0..16) wait
      if (bid == 0) {
        collect_publish(flags, genr, NP2, ph2);
      } else {
        bar_arrive(flags, ph2);
        if (bid <= NSEG) bar_waitgen(genr, ph2);
      }
    }

    // ---- P3 (blocks 0..16): reduce -> h; blk16 state/prob/argmax/word;
    //      blks 0..15: gh_in slice, poll word, h1/q/gho for t+1 ----
    if (bid <= NSEG) {
      for (int m = tid; m < 768; m += 512) {
        float g1 = bih_out[m];
        for (int s = 0; s < NCTX2; s++) g1 += ws[PGIO2_OFF + s * 768 + m];
        float g2 = bhh_out[m];
#pragma unroll
        for (int s = 0; s < NSEG; s++) g2 += ws[PGHO_OFF + s * 768 + m];
        sm_gio[m] = g1;
        sm_gho[m] = g2;
      }
      __syncthreads();
      if (tid < 256) {
        float h1v = ws[H1_OFF + tid];
        float r = sigmoidf_(sm_gio[tid] + sm_gho[tid]);
        float z = sigmoidf_(sm_gio[256 + tid] + sm_gho[256 + tid]);
        float n = tanhf(sm_gio[512 + tid] + r * sm_gho[512 + tid]);
        sm_h[tid] = (1.f - z) * n + z * h1v;
      }
      __syncthreads();
      if (bid == NSEG) {
        int word = words[t];  // written >=1 barrier ago (or k_init)
        if (tid < 128) {
          float s = bs_[tid] + bc_[tid] + ws[SE_OFF + word * 128 + tid];
          for (int sg = 0; sg < NCTX2; sg++) s += ws[PSC2_OFF + sg * 128 + tid];
          for (int k = 0; k < 256; k++) s += sm_h[k] * ws[WST_OFF + k * 128 + tid];
          sm_state[tid] = s;
        }
        __syncthreads();
        float best = -3.4e38f;
        int bi2 = 0;
        if (tid < V_DIM) {
          float p = bv_[tid];
          for (int k = 0; k < 128; k++) p += sm_state[k] * ws[WVT_OFF + k * V_DIM + tid];
          out[t * V_DIM + tid] = p;
          best = p;
          bi2 = tid;
        }
        sm_val[tid] = best;
        sm_idx[tid] = bi2;
        __syncthreads();
        for (int mstep = 256; mstep >= 1; mstep >>= 1) {
          if (tid < mstep) {
            float ov = sm_val[tid + mstep];
            int oi = sm_idx[tid + mstep];
            if (ov > sm_val[tid] || (ov == sm_val[tid] && oi < sm_idx[tid])) {
              sm_val[tid] = ov;
              sm_idx[tid] = oi;
            }
          }
          __syncthreads();
        }
        if (tid == 0)
          __hip_atomic_store(&words[t + 1], sm_idx[0], __ATOMIC_RELEASE, __HIP_MEMORY_SCOPE_AGENT);
      } else {
        // blocks 0..15: Whh_in slice from h(t)
        const int j0 = bid * 16;
        {
          int r = tid >> 3, l = tid & 7;
          if (r < 48) {
            int gate = r >> 4, jj = r & 15;
            int mg = gate * 256 + j0 + jj;
            const float* wr = Whh_in + mg * 256 + l * 32;
            float s = 0.f;
#pragma unroll
            for (int k = 0; k < 32; k++) s += sm_h[l * 32 + k] * wr[k];
#pragma unroll
            for (int off = 4; off; off >>= 1) s += __shfl_xor(s, off, 8);
            if (l == 0) sm_ghn[r] = s + bhh_in[mg];
          }
        }
        if (tid == 0) {
          int w, it = 0;
          while ((w = __hip_atomic_load(&words[t + 1], __ATOMIC_RELAXED, __HIP_MEMORY_SCOPE_AGENT)) < 0) {
            bk_sleep(it); ++it;
          }
          (void)__hip_atomic_load(&words[t + 1], __ATOMIC_ACQUIRE, __HIP_MEMORY_SCOPE_AGENT);
          sm_word = w;
        }
        __syncthreads();
        int wnew = sm_word;
        if (tid < 16) {
          int j = j0 + tid;
          const float* gi = ws + GI_OFF + wnew * 768;
          float r = sigmoidf_(gi[j] + sm_ghn[tid]);
          float z = sigmoidf_(gi[256 + j] + sm_ghn[16 + tid]);
          float n = tanhf(gi[512 + j] + r * sm_ghn[32 + tid]);
          float h1 = (1.f - z) * n + z * sm_h[j];
          ws[H1_OFF + j] = h1;
          sm_h1s[tid] = h1;
        }
        __syncthreads();
        {
          float s = 0.f;
#pragma unroll
          for (int kk = 0; kk < 16; kk++) s += sm_h1s[kk] * ws[WQT_OFF + (j0 + kk) * 512 + tid];
          ws[PQ_OFF + bid * 512 + tid] = s;
        }
        for (int m = tid; m < 768; m += 512) {
          float s = 0.f;
#pragma unroll
          for (int kk = 0; kk < 16; kk++) s += sm_h1s[kk] * ws[WHHTOUT_OFF + (j0 + kk) * 768 + m];
          ws[PGHO_OFF + bid * 768 + m] = s;
        }
      }
    }
    // bar3: 17 arrive; everyone waits
    if (bid == 0) {
      collect_publish(flags, genr, NSEG + 1, ph3);
    } else {
      if (bid <= NSEG) bar_arrive(flags, ph3);
      bar_waitgen(genr, ph3);
    }
  }
}

// ---------------- host ----------------

extern "C" void kernel_launch(void* const* d_in, const int* in_sizes, int n_in,
                              void* d_out, int out_size, void* d_ws, size_t ws_size,
                              hipStream_t stream) {
  (void)in_sizes; (void)n_in; (void)out_size; (void)ws_size;
  const float* cnn      = (const float*)d_in[0];
  const float* imask    = (const float*)d_in[1];
  const float* emb_tab  = (const float*)d_in[2];
  const float* W_init   = (const float*)d_in[3];
  const float* b_init   = (const float*)d_in[4];
  const float* Wih_in   = (const float*)d_in[5];
  const float* Whh_in   = (const float*)d_in[6];
  const float* bih_in   = (const float*)d_in[7];
  const float* bhh_in   = (const float*)d_in[8];
  const float* Wih_out  = (const float*)d_in[9];
  const float* Whh_out  = (const float*)d_in[10];
  const float* bih_out  = (const float*)d_in[11];
  const float* bhh_out  = (const float*)d_in[12];
  const float* Wq       = (const float*)d_in[13];
  const float* bq       = (const float*)d_in[14];
  const float* Wproj    = (const float*)d_in[15];
  const float* bproj    = (const float*)d_in[16];
  const float* convk    = (const float*)d_in[17];
  const float* Wcov     = (const float*)d_in[18];
  const float* wa       = (const float*)d_in[19];
  const float* ba       = (const float*)d_in[20];
  const float* Ws_      = (const float*)d_in[21];
  const float* bs_      = (const float*)d_in[22];
  const float* We_      = (const float*)d_in[23];
  const float* be_      = (const float*)d_in[24];
  const float* Wc_      = (const float*)d_in[25];
  const float* bc_      = (const float*)d_in[26];
  const float* Wv_      = (const float*)d_in[27];
  const float* bv_      = (const float*)d_in[28];
  float* ws  = (float*)d_ws;
  float* out = (float*)d_out;

  // one-time precompute
  k_init<<<1, 256, 0, stream>>>(imask, ws);
  k_avg<<<C_DIM, 256, 0, stream>>>(cnn, ws);
  k_h0<<<1, 256, 0, stream>>>(W_init, b_init, ws);
  k_km<<<121, 512, 0, stream>>>(convk, Wcov, ws);
  k_ct<<<dim3(HW / 128, A_DIM / 64), 256, 0, stream>>>(cnn, Wproj, bproj, ws);
  k_gi<<<V_DIM, 256, 0, stream>>>(emb_tab, Wih_in, bih_in, ws);
  k_se<<<V_DIM, 128, 0, stream>>>(emb_tab, We_, be_, ws);
  k_tr<<<512, 256, 0, stream>>>(Wq, ws + WQT_OFF, 512, 256);
  k_tr<<<512, 256, 0, stream>>>(Whh_out, ws + WHHTOUT_OFF, 768, 256);
  k_tr<<<512, 256, 0, stream>>>(Wih_out, ws + WIHTOUT_OFF, 768, 684);
  k_tr<<<512, 256, 0, stream>>>(Wc_, ws + WCT_OFF, 128, 684);
  k_tr<<<512, 256, 0, stream>>>(Ws_, ws + WST_OFF, 128, 256);
  k_tr<<<512, 256, 0, stream>>>(Wv_, ws + WVT_OFF, 415, 128);
  k_pre0<<<NSEG, 512, 0, stream>>>(Whh_in, bhh_in, ws);

  // all 64 steps in one persistent kernel
  k_steps<<<NBLK, 512, 0, stream>>>(cnn, Whh_in, bq, wa, ba, bih_out, bhh_out, bhh_in,
                                    bs_, bc_, bv_, ws, out);
}

// Round 5
// 5098.601 us; speedup vs baseline: 8.7075x; 2.7039x over previous
//
#include <hip/hip_runtime.h>
#include <math.h>

#define HF 32
#define WF 128
#define HW 4096
#define C_DIM 684
#define H_DIM 256
#define A_DIM 512
#define V_DIM 415
#define PADR 42
#define PADC 144
#define T_STEPS 64

#define NERG 128          // energy blocks: 32 h-rows x 4 a-quarters
#define NCTXB 86          // ctx blocks x 8 channels
#define CTX0 128
#define P3G0 214          // ghin blocks 214..229
#define STB 230           // state block
#define PRB0 231          // prob blocks 231,232
#define NGRID 233

// ---------------- workspace layout (float offsets) ----------------
constexpr int CT_OFF      = 0;                        // [4096][512] cnn_trans (+bproj)
constexpr int KMT_OFF     = CT_OFF + HW * A_DIM;      // [512][121] merged kernel^T
constexpr int APAD_OFF    = KMT_OFF + 512 * 121;      // [42][144]
constexpr int MASK_OFF    = APAD_OFF + PADR * PADC;   // [4096]
constexpr int PART_OFF    = MASK_OFF + HW;            // [4][4096] energy partials
constexpr int AVG_OFF     = PART_OFF + 4 * HW;        // [684] pad 704
constexpr int H0_OFF      = AVG_OFF + 704;            // [256]
constexpr int H1_OFF      = H0_OFF + 256;             // [2][256] ping-pong
constexpr int STATE_OFF   = H1_OFF + 512;             // [128]
constexpr int MSUM_OFF    = STATE_OFF + 128;          // [1] pad 16
constexpr int STF_OFF     = MSUM_OFF + 16;            // state flag line (ints)
constexpr int CAND0_OFF   = STF_OFF + 16;             // val,idx,seq
constexpr int CAND1_OFF   = CAND0_OFF + 16;
constexpr int FLAGS_OFF   = CAND1_OFF + 16;           // 256 * 16
constexpr int GENR_OFF    = FLAGS_OFF + 256 * 16;     // 8 * 16
constexpr int PQT_OFF     = GENR_OFF + 8 * 16;        // [2][512][16] q partials (transposed)
constexpr int PGHO_OFF    = PQT_OFF + 2 * 8192;       // [2][16][768]
constexpr int PGIO2_OFF   = PGHO_OFF + 2 * 12288;     // [86][768]
constexpr int PSC2_OFF    = PGIO2_OFF + NCTXB * 768;  // [86][128]
constexpr int GI_OFF      = PSC2_OFF + NCTXB * 128;   // [415][768]
constexpr int SE_OFF      = GI_OFF + V_DIM * 768;     // [415][128]
constexpr int WQT_OFF     = SE_OFF + V_DIM * 128;     // [256][512]
constexpr int WHHTOUT_OFF = WQT_OFF + 256 * 512;      // [256][768]
constexpr int WIHTOUT_OFF = WHHTOUT_OFF + 256 * 768;  // [684][768]
constexpr int WCT_OFF     = WIHTOUT_OFF + 684 * 768;  // [684][128]
constexpr int WST_OFF     = WCT_OFF + 684 * 128;      // [256][128]
constexpr int WVT_OFF     = WST_OFF + 256 * 128;      // [128][415]
constexpr int WS_END      = WVT_OFF + 128 * V_DIM;    // ~3.71M floats

__device__ __forceinline__ float sigmoidf_(float x) { return 1.f / (1.f + expf(-x)); }
__device__ __forceinline__ float ftanh(float x) {
  float e = __expf(2.f * x);
  return 1.f - 2.f / (e + 1.f);
}

__device__ __forceinline__ void bk_sleep(int it) {
  if (it < 2) __builtin_amdgcn_s_sleep(2);
  else if (it < 6) __builtin_amdgcn_s_sleep(16);
  else __builtin_amdgcn_s_sleep(64);
}
__device__ __forceinline__ void poll_ge(int* p, int ph) {
  int it = 0;
  while (__hip_atomic_load(p, __ATOMIC_RELAXED, __HIP_MEMORY_SCOPE_AGENT) < ph) {
    bk_sleep(it); ++it;
  }
  (void)__hip_atomic_load(p, __ATOMIC_ACQUIRE, __HIP_MEMORY_SCOPE_AGENT);
}
// block 0 only
__device__ __forceinline__ void collect_range(int* flags, int lo, int hi, int ph) {
  __syncthreads();
  int tid = threadIdx.x;
  if (tid >= lo && tid < hi) poll_ge(&flags[tid * 16], ph);
  __syncthreads();
}
__device__ __forceinline__ void publishgen(int* genr, int ph) {
  if (threadIdx.x < 8)
    __hip_atomic_store(&genr[threadIdx.x * 16], ph, __ATOMIC_RELEASE, __HIP_MEMORY_SCOPE_AGENT);
}
__device__ __forceinline__ void bar_arrive(int* flags, int ph) {
  __syncthreads();
  if (threadIdx.x == 0)
    __hip_atomic_store(&flags[blockIdx.x * 16], ph, __ATOMIC_RELEASE, __HIP_MEMORY_SCOPE_AGENT);
}
__device__ __forceinline__ void bar_waitgen(int* genr, int ph) {
  if (threadIdx.x == 0) poll_ge(&genr[(blockIdx.x & 7) * 16], ph);
  __syncthreads();
}

// ---------------- precompute kernels ----------------

__global__ void k_init(const float* __restrict__ imask, float* ws) {
  __shared__ float red[4];
  int tid = threadIdx.x;
  float s = 0.f;
  for (int i = tid; i < HW; i += 256) {
    int h = i >> 7, w = i & 127;
    float m = imask[h * 16 * 2048 + w * 16];
    ws[MASK_OFF + i] = m;
    s += m;
  }
  for (int i = tid; i < PADR * PADC; i += 256) ws[APAD_OFF + i] = 0.f;
  int* flags = (int*)(ws + FLAGS_OFF);
  for (int i = tid; i < 256 * 16; i += 256) flags[i] = 0;
  int* genr = (int*)(ws + GENR_OFF);
  if (tid < 8 * 16) genr[tid] = 0;
  if (tid < 16) {
    ((int*)(ws + STF_OFF))[tid] = 0;
    ((int*)(ws + CAND0_OFF))[tid] = 0;
    ((int*)(ws + CAND1_OFF))[tid] = 0;
  }
#pragma unroll
  for (int off = 32; off; off >>= 1) s += __shfl_xor(s, off, 64);
  if ((tid & 63) == 0) red[tid >> 6] = s;
  __syncthreads();
  if (tid == 0) ws[MSUM_OFF] = red[0] + red[1] + red[2] + red[3];
}

__global__ void k_avg(const float* __restrict__ cnn, float* ws) {
  __shared__ float red[4];
  int c = blockIdx.x, tid = threadIdx.x;
  const float* row = cnn + c * HW;
  float s = 0.f;
  for (int i = tid; i < HW; i += 256) s += ws[MASK_OFF + i] * row[i];
#pragma unroll
  for (int off = 32; off; off >>= 1) s += __shfl_xor(s, off, 64);
  if ((tid & 63) == 0) red[tid >> 6] = s;
  __syncthreads();
  if (tid == 0) ws[AVG_OFF + c] = (red[0] + red[1] + red[2] + red[3]) / ws[MSUM_OFF];
}

__global__ void k_h0(const float* __restrict__ W_init, const float* __restrict__ b_init, float* ws) {
  __shared__ float a_s[C_DIM];
  int tid = threadIdx.x;
  for (int i = tid; i < C_DIM; i += 256) a_s[i] = ws[AVG_OFF + i];
  __syncthreads();
  const float* wr = W_init + tid * C_DIM;
  float s = b_init[tid];
  for (int k = 0; k < C_DIM; k++) s += a_s[k] * wr[k];
  ws[H0_OFF + tid] = tanhf(s);
}

// merged coverage kernel, transposed: KMT[a][tap]
__global__ __launch_bounds__(512) void k_km(const float* __restrict__ convk,
                                            const float* __restrict__ Wcov, float* ws) {
  __shared__ float kt[256];
  int t = blockIdx.x, a = threadIdx.x;
  if (a < 256) kt[a] = convk[a * 121 + t];
  __syncthreads();
  const float* wr = Wcov + a * 256;
  float s = 0.f;
  for (int c = 0; c < 256; c++) s += kt[c] * wr[c];
  ws[KMT_OFF + a * 121 + t] = s;
}

__global__ void k_ct(const float* __restrict__ cnn, const float* __restrict__ Wproj,
                     const float* __restrict__ bproj, float* ws) {
  __shared__ float As[8][128];
  __shared__ float Bs[8][64];
  int hw0 = blockIdx.x * 128;
  int a0 = blockIdx.y * 64;
  int tid = threadIdx.x;
  int tx = tid & 15, ty = tid >> 4;
  float acc[8][4];
#pragma unroll
  for (int i = 0; i < 8; i++)
#pragma unroll
    for (int j = 0; j < 4; j++) acc[i][j] = 0.f;

  for (int c0 = 0; c0 < C_DIM; c0 += 8) {
    {
      int kk = tid >> 5;
      int m4 = (tid & 31) * 4;
      int c = c0 + kk;
      float4 v = make_float4(0.f, 0.f, 0.f, 0.f);
      if (c < C_DIM) v = *(const float4*)(cnn + c * HW + hw0 + m4);
      *(float4*)&As[kk][m4] = v;
    }
    {
      int n = tid & 63;
      int kk0 = (tid >> 6) * 2;
      const float* wr = Wproj + (a0 + n) * C_DIM + c0;
      Bs[kk0][n]     = (c0 + kk0 < C_DIM) ? wr[kk0] : 0.f;
      Bs[kk0 + 1][n] = (c0 + kk0 + 1 < C_DIM) ? wr[kk0 + 1] : 0.f;
    }
    __syncthreads();
#pragma unroll
    for (int kk = 0; kk < 8; kk++) {
      float a8[8], b4[4];
#pragma unroll
      for (int i = 0; i < 8; i++) a8[i] = As[kk][ty * 8 + i];
#pragma unroll
      for (int j = 0; j < 4; j++) b4[j] = Bs[kk][tx * 4 + j];
#pragma unroll
      for (int i = 0; i < 8; i++)
#pragma unroll
        for (int j = 0; j < 4; j++) acc[i][j] += a8[i] * b4[j];
    }
    __syncthreads();
  }
#pragma unroll
  for (int i = 0; i < 8; i++) {
    int hw = hw0 + ty * 8 + i;
#pragma unroll
    for (int j = 0; j < 4; j++) {
      int a = a0 + tx * 4 + j;
      ws[CT_OFF + hw * A_DIM + a] = acc[i][j] + bproj[a];
    }
  }
}

__global__ void k_gi(const float* __restrict__ emb_table, const float* __restrict__ Wih_in,
                     const float* __restrict__ bih_in, float* ws) {
  __shared__ float e_s[256];
  int v = blockIdx.x, tid = threadIdx.x;
  e_s[tid] = emb_table[v * 256 + tid];
  __syncthreads();
#pragma unroll
  for (int r = 0; r < 3; r++) {
    int m = r * 256 + tid;
    const float* wr = Wih_in + m * 256;
    float s = bih_in[m];
    for (int k = 0; k < 256; k++) s += e_s[k] * wr[k];
    ws[GI_OFF + v * 768 + m] = s;
  }
}

__global__ void k_se(const float* __restrict__ emb_table, const float* __restrict__ We,
                     const float* __restrict__ be, float* ws) {
  __shared__ float e_s[256];
  int v = blockIdx.x, tid = threadIdx.x;  // 128 threads
  e_s[tid] = emb_table[v * 256 + tid];
  e_s[tid + 128] = emb_table[v * 256 + tid + 128];
  __syncthreads();
  const float* wr = We + tid * 256;
  float s = be[tid];
  for (int k = 0; k < 256; k++) s += e_s[k] * wr[k];
  ws[SE_OFF + v * 128 + tid] = s;
}

__global__ void k_tr(const float* __restrict__ in, float* __restrict__ out, int M, int Kd) {
  int total = M * Kd;
  for (int i = blockIdx.x * blockDim.x + threadIdx.x; i < total; i += gridDim.x * blockDim.x) {
    int m = i / Kd, k = i - m * Kd;
    out[k * M + m] = in[i];
  }
}

// step-0 bootstrap: h1(0) slice + PQT(0)/PGHO(0), from h0 and word=1
__global__ __launch_bounds__(512) void k_pre0(const float* __restrict__ Whh_in,
                                              const float* __restrict__ bhh_in, float* ws) {
  __shared__ float sm_hh[256];
  __shared__ float sm_ghn[48];
  __shared__ float sm_h1s[16];
  const int bid = blockIdx.x, tid = threadIdx.x;
  const int j0 = bid * 16;
  if (tid < 256) sm_hh[tid] = ws[H0_OFF + tid];
  __syncthreads();
  {
    int r = tid >> 3, l = tid & 7;
    if (r < 48) {
      int gate = r >> 4, jj = r & 15;
      int mg = gate * 256 + j0 + jj;
      const float* wr = Whh_in + mg * 256 + l * 32;
      float s = 0.f;
#pragma unroll
      for (int k = 0; k < 32; k++) s += sm_hh[l * 32 + k] * wr[k];
#pragma unroll
      for (int off = 4; off; off >>= 1) s += __shfl_xor(s, off, 8);
      if (l == 0) sm_ghn[r] = s + bhh_in[mg];
    }
  }
  __syncthreads();
  if (tid < 16) {
    int j = j0 + tid;
    const float* gi = ws + GI_OFF + 1 * 768;  // word 1
    float r = sigmoidf_(gi[j] + sm_ghn[tid]);
    float z = sigmoidf_(gi[256 + j] + sm_ghn[16 + tid]);
    float n = tanhf(gi[512 + j] + r * sm_ghn[32 + tid]);
    float h1 = (1.f - z) * n + z * sm_hh[j];
    ws[H1_OFF + j] = h1;  // slot 0
    sm_h1s[tid] = h1;
  }
  __syncthreads();
  {
    float s = 0.f;
#pragma unroll
    for (int kk = 0; kk < 16; kk++) s += sm_h1s[kk] * ws[WQT_OFF + (j0 + kk) * 512 + tid];
    ws[PQT_OFF + tid * 16 + bid] = s;  // slot 0, transposed
  }
  for (int m = tid; m < 768; m += 512) {
    float s = 0.f;
#pragma unroll
    for (int kk = 0; kk < 16; kk++) s += sm_h1s[kk] * ws[WHHTOUT_OFF + (j0 + kk) * 768 + m];
    ws[PGHO_OFF + bid * 768 + m] = s;  // slot 0
  }
}

// ---------------- persistent all-steps kernel, role-specialized ----------------

__global__ __launch_bounds__(512) void k_steps(
    const float* __restrict__ cnn, const float* __restrict__ Whh_in,
    const float* __restrict__ bq, const float* __restrict__ wa, const float* __restrict__ ba,
    const float* __restrict__ bih_out, const float* __restrict__ bhh_out,
    const float* __restrict__ bhh_in,
    const float* __restrict__ bs_, const float* __restrict__ bc_, const float* __restrict__ bv_,
    float* ws, float* __restrict__ out) {
  __shared__ float S[40016];  // ~160 KB, carved per role

  const int bid = blockIdx.x, tid = threadIdx.x;
  int* flags = (int*)(ws + FLAGS_OFF);
  int* genr  = (int*)(ws + GENR_OFF);

  if (bid < NERG) {
    // ================= ENERGY role =================
    const int h_row = bid >> 2, aq = bid & 3, a0 = aq * 128;
    const int al = tid & 127, hslot = tid >> 7;
    float* km    = S;          // [al][121]
    float* ct    = S + 15488;  // [w][al]
    float* patch = S + 31872;  // [11][144]
    float* maskv = S + 33456;  // [128]
    float* redE  = S + 33584;  // [8][16]
    for (int i = tid; i < 128 * 121; i += 512) km[i] = ws[KMT_OFF + a0 * 121 + i];
    for (int i = tid; i < 128 * 128; i += 512) {
      int w = i >> 7, aa = i & 127;
      ct[i] = ws[CT_OFF + (h_row * 128 + w) * 512 + a0 + aa];
    }
    if (tid < 128) maskv[tid] = ws[MASK_OFF + h_row * 128 + tid];
    const float bq_a = bq[a0 + al], wa_a = wa[a0 + al], ba0 = ba[0];
    __syncthreads();

#pragma unroll 1
    for (int t = 0; t < T_STEPS; t++) {
      const int ph1 = 3 * t + 1, ph2 = 3 * t + 2, ph3 = 3 * t + 3;
      float qa = bq_a;
      {
        const float* pq = ws + PQT_OFF + (t & 1) * 8192 + (a0 + al) * 16;
#pragma unroll
        for (int s = 0; s < 16; s++) qa += pq[s];
      }
      for (int i = tid; i < 11 * 138; i += 512) {
        int r = i / 138, c = i - r * 138;
        patch[r * 144 + c] = ws[APAD_OFF + (h_row + r) * PADC + c];
      }
      __syncthreads();
#pragma unroll 1
      for (int p = 0; p < 2; p++) {
        const int wbase = hslot * 32 + p * 16;
        float acc[16];
#pragma unroll
        for (int i = 0; i < 16; i++) acc[i] = 0.f;
        for (int dy = 0; dy < 11; dy++) {
          float row[26];
#pragma unroll
          for (int i = 0; i < 26; i++) row[i] = patch[dy * 144 + wbase + i];
          float kv[11];
#pragma unroll
          for (int dx = 0; dx < 11; dx++) kv[dx] = km[al * 121 + dy * 11 + dx];
#pragma unroll
          for (int dx = 0; dx < 11; dx++)
#pragma unroll
            for (int wi = 0; wi < 16; wi++) acc[wi] += kv[dx] * row[wi + dx];
        }
#pragma unroll
        for (int wi = 0; wi < 16; wi++) {
          float x = acc[wi] + qa + ct[(wbase + wi) * 128 + al];
          float v = ftanh(x) * wa_a;
#pragma unroll
          for (int off = 32; off; off >>= 1) v += __shfl_xor(v, off, 64);
          if ((tid & 63) == 0) redE[(tid >> 6) * 16 + wi] = v;
        }
        __syncthreads();
        if (tid < 64) {
          int hs2 = tid >> 4, wi = tid & 15;
          int w = hs2 * 32 + p * 16 + wi;
          float e = redE[(hs2 * 2) * 16 + wi] + redE[(hs2 * 2 + 1) * 16 + wi];
          float val = (maskv[w] > 0.f) ? (e + (aq == 0 ? ba0 : 0.f)) : -2.5e8f;
          ws[PART_OFF + aq * 4096 + h_row * 128 + w] = val;
        }
        __syncthreads();
      }
      if (bid == 0) {
        collect_range(flags, 1, NERG, ph1);        publishgen(genr, ph1);
        collect_range(flags, CTX0, P3G0, ph2);     publishgen(genr, ph2);
        collect_range(flags, P3G0, STB + 1, ph3);  publishgen(genr, ph3);
      } else {
        bar_arrive(flags, ph1);
        bar_waitgen(genr, ph3);
      }
    }

  } else if (bid < CTX0 + NCTXB) {
    // ================= CTX role =================
    const int cb = bid - CTX0, c0 = cb * 8;
    float* cnnS = S;           // [8][4096]
    float* wio  = S + 32768;   // [8][768]
    float* wct  = S + 38912;   // [8][128]
    float* redC = S + 39936;   // [8 waves][8]
    float* ctxv = S + 40000;   // [8]
    float* invp = S + 40008;
    for (int i = tid; i < 8 * 4096; i += 512) {
      int c = c0 + (i >> 12);
      cnnS[i] = (c < C_DIM) ? cnn[c * 4096 + (i & 4095)] : 0.f;
    }
    for (int i = tid; i < 8 * 768; i += 512) {
      int c = c0 + i / 768;
      wio[i] = (c < C_DIM) ? ws[WIHTOUT_OFF + c * 768 + (i % 768)] : 0.f;
    }
    for (int i = tid; i < 8 * 128; i += 512) {
      int c = c0 + (i >> 7);
      wct[i] = (c < C_DIM) ? ws[WCT_OFF + c * 128 + (i & 127)] : 0.f;
    }
    __syncthreads();

#pragma unroll 1
    for (int t = 0; t < T_STEPS; t++) {
      const int ph1 = 3 * t + 1, ph2 = 3 * t + 2;
      bar_waitgen(genr, ph1);
      float ev[8];
      float ssum = 0.f;
#pragma unroll
      for (int j = 0; j < 8; j++) {
        int hw = j * 512 + tid;
        float e = ws[PART_OFF + hw] + ws[PART_OFF + 4096 + hw] +
                  ws[PART_OFF + 8192 + hw] + ws[PART_OFF + 12288 + hw];
        ev[j] = __expf(e);
        ssum += ev[j];
      }
#pragma unroll
      for (int off = 32; off; off >>= 1) ssum += __shfl_xor(ssum, off, 64);
      if ((tid & 63) == 0) redC[tid >> 6] = ssum;
      __syncthreads();
      if (tid == 0) {
        float s2 = 0.f;
#pragma unroll
        for (int i = 0; i < 8; i++) s2 += redC[i];
        invp[0] = 1.f / s2;
      }
      __syncthreads();
      float inv = invp[0];
      if (cb < 8) {
        int hw = cb * 512 + tid;
        int hh = hw >> 7, ww = hw & 127;
        ws[APAD_OFF + (hh + 5) * PADC + ww + 5] += ev[cb] * inv;
      }
#pragma unroll
      for (int cc = 0; cc < 8; cc++) {
        float p = 0.f;
#pragma unroll
        for (int j = 0; j < 8; j++) p += ev[j] * cnnS[cc * 4096 + j * 512 + tid];
#pragma unroll
        for (int off = 32; off; off >>= 1) p += __shfl_xor(p, off, 64);
        if ((tid & 63) == 0) redC[(tid >> 6) * 8 + cc] = p;
      }
      __syncthreads();
      if (tid < 8) {
        float cv = 0.f;
#pragma unroll
        for (int w2 = 0; w2 < 8; w2++) cv += redC[w2 * 8 + tid];
        ctxv[tid] = cv * inv;
      }
      __syncthreads();
      for (int m = tid; m < 768; m += 512) {
        float s2 = 0.f;
#pragma unroll
        for (int cc = 0; cc < 8; cc++) s2 += ctxv[cc] * wio[cc * 768 + m];
        ws[PGIO2_OFF + cb * 768 + m] = s2;
      }
      if (tid < 128) {
        float s2 = 0.f;
#pragma unroll
        for (int cc = 0; cc < 8; cc++) s2 += ctxv[cc] * wct[cc * 128 + tid];
        ws[PSC2_OFF + cb * 128 + tid] = s2;
      }
      bar_arrive(flags, ph2);
    }

  } else if (bid < STB) {
    // ================= GHIN role (16 blocks) =================
    const int seg = bid - P3G0, j0 = seg * 16;
    float* wqtS  = S;          // [16][512]
    float* whtS  = S + 8192;   // [16][768]
    float* whinS = S + 20480;  // [48][256]
    float* gio   = S + 32768;
    float* gho   = S + 33536;
    float* hS    = S + 34304;
    float* ghn   = S + 34560;
    float* h1s   = S + 34608;
    int*   wrd   = (int*)(S + 34624);
    for (int i = tid; i < 16 * 512; i += 512) wqtS[i] = ws[WQT_OFF + (j0 + (i >> 9)) * 512 + (i & 511)];
    for (int i = tid; i < 16 * 768; i += 512) wqtS[8192 + i] = ws[WHHTOUT_OFF + (j0 + i / 768) * 768 + (i % 768)];
    for (int i = tid; i < 48 * 256; i += 512) {
      int r = i >> 8;
      int mg = (r >> 4) * 256 + j0 + (r & 15);
      whinS[i] = Whh_in[mg * 256 + (i & 255)];
    }
    __syncthreads();

#pragma unroll 1
    for (int t = 0; t < T_STEPS; t++) {
      const int ph2 = 3 * t + 2, ph3 = 3 * t + 3;
      const int par = t & 1;
      bar_waitgen(genr, ph2);
      for (int m = tid; m < 768; m += 512) {
        float g1 = bih_out[m];
#pragma unroll 8
        for (int cb = 0; cb < NCTXB; cb++) g1 += ws[PGIO2_OFF + cb * 768 + m];
        float g2 = bhh_out[m];
#pragma unroll
        for (int s2 = 0; s2 < 16; s2++) g2 += ws[PGHO_OFF + par * 12288 + s2 * 768 + m];
        gio[m] = g1;
        gho[m] = g2;
      }
      __syncthreads();
      if (tid < 256) {
        float h1v = ws[H1_OFF + par * 256 + tid];
        float r = sigmoidf_(gio[tid] + gho[tid]);
        float z = sigmoidf_(gio[256 + tid] + gho[256 + tid]);
        float n = tanhf(gio[512 + tid] + r * gho[512 + tid]);
        hS[tid] = (1.f - z) * n + z * h1v;
      }
      __syncthreads();
      {
        int r = tid >> 3, l = tid & 7;
        if (r < 48) {
          float s2 = 0.f;
#pragma unroll
          for (int k = 0; k < 32; k++) s2 += hS[l * 32 + k] * whinS[r * 256 + l * 32 + k];
#pragma unroll
          for (int off = 4; off; off >>= 1) s2 += __shfl_xor(s2, off, 8);
          if (l == 0) ghn[r] = s2 + bhh_in[(r >> 4) * 256 + j0 + (r & 15)];
        }
      }
      if (tid == 0) {
        int* c0i = (int*)(ws + CAND0_OFF);
        int* c1i = (int*)(ws + CAND1_OFF);
        poll_ge(&c0i[2], t + 1);
        poll_ge(&c1i[2], t + 1);
        float v0 = ((float*)c0i)[0], v1 = ((float*)c1i)[0];
        wrd[0] = (v0 >= v1) ? c0i[1] : c1i[1];
      }
      __syncthreads();
      int word = wrd[0];
      if (tid < 16) {
        int j = j0 + tid;
        const float* gi = ws + GI_OFF + word * 768;
        float r = sigmoidf_(gi[j] + ghn[tid]);
        float z = sigmoidf_(gi[256 + j] + ghn[16 + tid]);
        float n = tanhf(gi[512 + j] + r * ghn[32 + tid]);
        float h1 = (1.f - z) * n + z * hS[j];
        ws[H1_OFF + (par ^ 1) * 256 + j] = h1;
        h1s[tid] = h1;
      }
      __syncthreads();
      {
        float s2 = 0.f;
#pragma unroll
        for (int kk = 0; kk < 16; kk++) s2 += h1s[kk] * wqtS[kk * 512 + tid];
        ws[PQT_OFF + (par ^ 1) * 8192 + tid * 16 + seg] = s2;
      }
      for (int m = tid; m < 768; m += 512) {
        float s2 = 0.f;
#pragma unroll
        for (int kk = 0; kk < 16; kk++) s2 += h1s[kk] * whtS[kk * 768 + m];
        ws[PGHO_OFF + (par ^ 1) * 12288 + seg * 768 + m] = s2;
      }
      bar_arrive(flags, ph3);
    }

  } else if (bid == STB) {
    // ================= STATE role =================
    float* wst = S;            // [256][128]
    float* gio = S + 32768;
    float* gho = S + 33536;
    float* hS  = S + 34304;
    int*   wrd = (int*)(S + 34688);
    for (int i = tid; i < 256 * 128; i += 512) wst[i] = ws[WST_OFF + i];
    __syncthreads();

#pragma unroll 1
    for (int t = 0; t < T_STEPS; t++) {
      const int ph2 = 3 * t + 2, ph3 = 3 * t + 3;
      const int par = t & 1;
      bar_waitgen(genr, ph2);
      for (int m = tid; m < 768; m += 512) {
        float g1 = bih_out[m];
#pragma unroll 8
        for (int cb = 0; cb < NCTXB; cb++) g1 += ws[PGIO2_OFF + cb * 768 + m];
        float g2 = bhh_out[m];
#pragma unroll
        for (int s2 = 0; s2 < 16; s2++) g2 += ws[PGHO_OFF + par * 12288 + s2 * 768 + m];
        gio[m] = g1;
        gho[m] = g2;
      }
      __syncthreads();
      if (tid < 256) {
        float h1v = ws[H1_OFF + par * 256 + tid];
        float r = sigmoidf_(gio[tid] + gho[tid]);
        float z = sigmoidf_(gio[256 + tid] + gho[256 + tid]);
        float n = tanhf(gio[512 + tid] + r * gho[512 + tid]);
        hS[tid] = (1.f - z) * n + z * h1v;
      }
      __syncthreads();
      if (tid == 0) {
        int w;
        if (t == 0) w = 1;
        else {
          int* c0i = (int*)(ws + CAND0_OFF);
          int* c1i = (int*)(ws + CAND1_OFF);
          float v0 = ((float*)c0i)[0], v1 = ((float*)c1i)[0];
          w = (v0 >= v1) ? c0i[1] : c1i[1];
        }
        wrd[0] = w;
      }
      __syncthreads();
      int word = wrd[0];
      if (tid < 128) {
        float s2 = bs_[tid] + bc_[tid] + ws[SE_OFF + word * 128 + tid];
#pragma unroll 8
        for (int cb = 0; cb < NCTXB; cb++) s2 += ws[PSC2_OFF + cb * 128 + tid];
#pragma unroll 16
        for (int k = 0; k < 256; k++) s2 += hS[k] * wst[k * 128 + tid];
        ws[STATE_OFF + tid] = s2;
      }
      __syncthreads();
      if (tid == 0)
        __hip_atomic_store((int*)(ws + STF_OFF), t + 1, __ATOMIC_RELEASE, __HIP_MEMORY_SCOPE_AGENT);
      bar_arrive(flags, ph3);
    }

  } else {
    // ================= PROB role (2 blocks, barrier-free) =================
    const int half = bid - PRB0;
    const int v0 = half * 208;
    const int nv = (half == 0) ? 208 : 207;
    float* wvt  = S;           // [128][208]
    float* stt  = S + 26624;   // [128]
    float* sval = S + 26752;   // [512]
    int*   sidx = (int*)(S + 27264);
    for (int i = tid; i < 128 * 208; i += 512) {
      int k = i / 208, v = i - k * 208;
      wvt[i] = (v0 + v < V_DIM) ? ws[WVT_OFF + k * V_DIM + v0 + v] : 0.f;
    }
    __syncthreads();

#pragma unroll 1
    for (int t = 0; t < T_STEPS; t++) {
      if (tid == 0) poll_ge((int*)(ws + STF_OFF), t + 1);
      __syncthreads();
      if (tid < 128) stt[tid] = ws[STATE_OFF + tid];
      __syncthreads();
      float best = -3.4e38f;
      int bi = 0;
      if (tid < nv) {
        float p = bv_[v0 + tid];
#pragma unroll 16
        for (int k = 0; k < 128; k++) p += stt[k] * wvt[k * 208 + tid];
        out[t * V_DIM + v0 + tid] = p;
        best = p;
        bi = v0 + tid;
      }
      sval[tid] = best;
      sidx[tid] = bi;
      __syncthreads();
      for (int m = 256; m >= 1; m >>= 1) {
        if (tid < m) {
          float ov = sval[tid + m];
          int oi = sidx[tid + m];
          if (ov > sval[tid] || (ov == sval[tid] && oi < sidx[tid])) {
            sval[tid] = ov;
            sidx[tid] = oi;
          }
        }
        __syncthreads();
      }
      if (tid == 0) {
        int* ci = (int*)(ws + (half ? CAND1_OFF : CAND0_OFF));
        ((float*)ci)[0] = sval[0];
        ci[1] = sidx[0];
        __hip_atomic_store(&ci[2], t + 1, __ATOMIC_RELEASE, __HIP_MEMORY_SCOPE_AGENT);
      }
      __syncthreads();
    }
  }
}

// ---------------- host ----------------

extern "C" void kernel_launch(void* const* d_in, const int* in_sizes, int n_in,
                              void* d_out, int out_size, void* d_ws, size_t ws_size,
                              hipStream_t stream) {
  (void)in_sizes; (void)n_in; (void)out_size; (void)ws_size;
  const float* cnn      = (const float*)d_in[0];
  const float* imask    = (const float*)d_in[1];
  const float* emb_tab  = (const float*)d_in[2];
  const float* W_init   = (const float*)d_in[3];
  const float* b_init   = (const float*)d_in[4];
  const float* Wih_in   = (const float*)d_in[5];
  const float* Whh_in   = (const float*)d_in[6];
  const float* bih_in   = (const float*)d_in[7];
  const float* bhh_in   = (const float*)d_in[8];
  const float* Wih_out  = (const float*)d_in[9];
  const float* Whh_out  = (const float*)d_in[10];
  const float* bih_out  = (const float*)d_in[11];
  const float* bhh_out  = (const float*)d_in[12];
  const float* Wq       = (const float*)d_in[13];
  const float* bq       = (const float*)d_in[14];
  const float* Wproj    = (const float*)d_in[15];
  const float* bproj    = (const float*)d_in[16];
  const float* convk    = (const float*)d_in[17];
  const float* Wcov     = (const float*)d_in[18];
  const float* wa       = (const float*)d_in[19];
  const float* ba       = (const float*)d_in[20];
  const float* Ws_      = (const float*)d_in[21];
  const float* bs_      = (const float*)d_in[22];
  const float* We_      = (const float*)d_in[23];
  const float* be_      = (const float*)d_in[24];
  const float* Wc_      = (const float*)d_in[25];
  const float* bc_      = (const float*)d_in[26];
  const float* Wv_      = (const float*)d_in[27];
  const float* bv_      = (const float*)d_in[28];
  float* ws  = (float*)d_ws;
  float* out = (float*)d_out;

  // one-time precompute
  k_init<<<1, 256, 0, stream>>>(imask, ws);
  k_avg<<<C_DIM, 256, 0, stream>>>(cnn, ws);
  k_h0<<<1, 256, 0, stream>>>(W_init, b_init, ws);
  k_km<<<121, 512, 0, stream>>>(convk, Wcov, ws);
  k_ct<<<dim3(HW / 128, A_DIM / 64), 256, 0, stream>>>(cnn, Wproj, bproj, ws);
  k_gi<<<V_DIM, 256, 0, stream>>>(emb_tab, Wih_in, bih_in, ws);
  k_se<<<V_DIM, 128, 0, stream>>>(emb_tab, We_, be_, ws);
  k_tr<<<512, 256, 0, stream>>>(Wq, ws + WQT_OFF, 512, 256);
  k_tr<<<512, 256, 0, stream>>>(Whh_out, ws + WHHTOUT_OFF, 768, 256);
  k_tr<<<512, 256, 0, stream>>>(Wih_out, ws + WIHTOUT_OFF, 768, 684);
  k_tr<<<512, 256, 0, stream>>>(Wc_, ws + WCT_OFF, 128, 684);
  k_tr<<<512, 256, 0, stream>>>(Ws_, ws + WST_OFF, 128, 256);
  k_tr<<<512, 256, 0, stream>>>(Wv_, ws + WVT_OFF, 415, 128);
  k_pre0<<<16, 512, 0, stream>>>(Whh_in, bhh_in, ws);

  // all 64 steps in one persistent, role-specialized kernel
  k_steps<<<NGRID, 512, 0, stream>>>(cnn, Whh_in, bq, wa, ba, bih_out, bhh_out, bhh_in,
                                     bs_, bc_, bv_, ws, out);
}